// Round 5
// baseline (296.769 us; speedup 1.0000x reference)
//
#include <hip/hip_runtime.h>
#include <hip/hip_bf16.h>

typedef unsigned short u16;
typedef unsigned int   u32;
typedef __attribute__((ext_vector_type(8))) short short8;   // 8 bf16 (4 VGPRs)
typedef __attribute__((ext_vector_type(4))) float f32x4;

#define T_ROWS    131072
#define SC_CHUNK  2            // rows per chunk in the fused scan
#define WARM      8            // rho<=0.34 -> 0.34^8 ~ 1.8e-4
#define NBLK_SCAN 1024         // 1024 blocks * 4 waves * 16 chunks * 2 rows = 131072
#define PSTRIDE   70           // preL row stride in u16
#define PTILES    9            // 9 tiles of 16 rows = 144 >= 128 + 8 warm
#define PROWS     (PTILES * 16)

// ws layout (float offsets)
#define WS_SUM   0             // 256 f
#define WS_SQ    256           // 256 f
#define WS_CJ    512           // 64 f  (b1 + shift@W1 folded)
#define WS_WEF   576           // 8192 u32: We bf16 in MFMA B-frag order [ks*4+nt][lane][j(8)]
#define WS_NEED  ((size_t)(WS_WEF + 8192) * 4)                // ~35 KB

__device__ __forceinline__ u16 f2bf(float f) {   // RNE float->bf16
  u32 u = __float_as_uint(f);
  u += 0x7FFFu + ((u >> 16) & 1u);
  return (u16)(u >> 16);
}
__device__ __forceinline__ u32 packbf(float a, float b) {
  return (u32)f2bf(a) | ((u32)f2bf(b) << 16);
}
__device__ __forceinline__ float bfl(u32 u) { return __uint_as_float(u << 16); }
__device__ __forceinline__ float bfh(u32 u) { return __uint_as_float(u & 0xFFFF0000u); }

__global__ void k_zero(float* ws) { ws[threadIdx.x] = 0.0f; }   // <<<1,512>>>

__global__ void k_sentinel(float* out) { out[threadIdx.x] = 12345.0f; }

// ---- column mean / sumsq over x[131072][256], grid 1024 x 256 thr (proven) ----
__global__ __launch_bounds__(256) void k_stats(const float* __restrict__ x,
                                               float* __restrict__ ws) {
  __shared__ float lsum[1024];
  __shared__ float lsq[1024];
  const int tid = threadIdx.x;
  const int lane = tid & 63;
  const int w = tid >> 6;
  const int c = lane * 4;
  float s0 = 0, s1 = 0, s2 = 0, s3 = 0;
  float q0 = 0, q1 = 0, q2 = 0, q3 = 0;
  const size_t rbase = (size_t)blockIdx.x * 128;
#pragma unroll 4
  for (int i = w; i < 128; i += 4) {
    const float4 v = *(const float4*)(x + (rbase + i) * 256 + c);
    s0 += v.x; s1 += v.y; s2 += v.z; s3 += v.w;
    q0 = fmaf(v.x, v.x, q0); q1 = fmaf(v.y, v.y, q1);
    q2 = fmaf(v.z, v.z, q2); q3 = fmaf(v.w, v.w, q3);
  }
  lsum[w * 256 + c + 0] = s0; lsum[w * 256 + c + 1] = s1;
  lsum[w * 256 + c + 2] = s2; lsum[w * 256 + c + 3] = s3;
  lsq [w * 256 + c + 0] = q0; lsq [w * 256 + c + 1] = q1;
  lsq [w * 256 + c + 2] = q2; lsq [w * 256 + c + 3] = q3;
  __syncthreads();
  const float ts = lsum[tid] + lsum[256 + tid] + lsum[512 + tid] + lsum[768 + tid];
  const float tq = lsq [tid] + lsq [256 + tid] + lsq [512 + tid] + lsq [768 + tid];
  atomicAdd(ws + WS_SUM + tid, ts);
  atomicAdd(ws + WS_SQ  + tid, tq);
}

// ---- fold BN into weights. Emits We = scale*W1[:256] in MFMA B-frag order. 512 thr. (proven) ----
__global__ __launch_bounds__(512) void k_prep(const float* __restrict__ gamma,
                                              const float* __restrict__ beta,
                                              const float* __restrict__ W1,
                                              const float* __restrict__ b1,
                                              float* __restrict__ ws) {
  __shared__ float sScale[256];
  __shared__ float sShift[256];
  __shared__ float sCj[512];
  const int tid = threadIdx.x;
  if (tid < 256) {
    const float inv = 1.0f / (float)T_ROWS;
    const float mean = ws[WS_SUM + tid] * inv;
    const float var  = ws[WS_SQ + tid] * inv - mean * mean;   // biased, keras BN
    const float sc = gamma[tid] * rsqrtf(var + 1e-3f);
    sScale[tid] = sc;
    sShift[tid] = beta[tid] - mean * sc;
  }
  __syncthreads();
  if (tid < 256) {
    const int nt = tid >> 6;
    const int lane = tid & 63;
    const int m = lane & 15;
    const int q = lane >> 4;
    const int n = nt * 16 + m;
    u32* Wf = (u32*)(ws + WS_WEF);
#pragma unroll
    for (int ks = 0; ks < 8; ++ks) {
      uint4 pk;
      u32 w_[4];
#pragma unroll
      for (int jj = 0; jj < 4; ++jj) {
        const int k0 = ks * 32 + q * 8 + 2 * jj;
        const u32 lo = f2bf(sScale[k0]     * W1[(size_t)k0 * 64 + n]);
        const u32 hi = f2bf(sScale[k0 + 1] * W1[(size_t)(k0 + 1) * 64 + n]);
        w_[jj] = lo | (hi << 16);
      }
      pk.x = w_[0]; pk.y = w_[1]; pk.z = w_[2]; pk.w = w_[3];
      *(uint4*)(Wf + (size_t)((ks * 4 + nt) * 64 + lane) * 4) = pk;
    }
  }
  // cj[j] = b1[j] + sum_c sShift[c]*W1[c][j], 8-way split over c then LDS combine
  const int j = tid & 63;
  const int part = tid >> 6;            // 0..7
  float p = (part == 0) ? b1[j] : 0.0f;
  for (int c = part * 32; c < part * 32 + 32; ++c)
    p = fmaf(sShift[c], W1[(size_t)c * 64 + j], p);
  sCj[tid] = p;
  __syncthreads();
  if (tid < 64) {
    float a = 0.0f;
#pragma unroll
    for (int k = 0; k < 8; ++k) a += sCj[k * 64 + tid];
    ws[WS_CJ + tid] = a;
  }
}

// ---- FUSED gemm+scan: 1024 blocks x (128 rows + 8 warm). LDS 37.6 KB -> 4 blocks/CU,
//      16 waves/CU (2x round-3 latency hiding). B-frags from L2 per tile (VGPR <= 128). ----
struct P4 { uint2 v[4]; };

__global__ __launch_bounds__(256, 4) void k_gemm_scan(
    const float* __restrict__ x, const float* __restrict__ ws,
    const float* __restrict__ W1, const float* __restrict__ W2,
    const float* __restrict__ b2, const float* __restrict__ W3,
    const float* __restrict__ b3, float* __restrict__ out) {
  __shared__ __align__(16) u16 preL[PROWS * PSTRIDE];   // 20160 B
  __shared__ __align__(16) u16 sL1[4][16 * 88];         // 11264 B, per-wave h1 tile
  __shared__ __align__(16) u16 sL2[4][16 * 40];         //  5120 B, per-wave h2 tile
  __shared__ __align__(16) u16 sL3[4][16 * 8];          //  1024 B, per-wave h tile

  const int lane = threadIdx.x & 63;
  const int w    = threadIdx.x >> 6;
  const int l15  = lane & 15;
  const int q    = lane >> 4;
  const int B    = blockIdx.x;

  // ================= GEMM phase: 9 tiles of 16 rows into preL =================
  {
    const u32* Bf = (const u32*)(ws + WS_WEF);
    float cw[4];
#pragma unroll
    for (int nt = 0; nt < 4; ++nt) cw[nt] = ws[WS_CJ + nt * 16 + l15];
    const int rowOrigin = B * 128 - 8;
    for (int tt = w; tt < PTILES; tt += 4) {
      int gr = rowOrigin + tt * 16 + l15;               // clamp: edge rows junk, unused/reset
      gr = gr < 0 ? 0 : (gr > T_ROWS - 1 ? T_ROWS - 1 : gr);
      const float* xr = x + (size_t)gr * 256 + q * 8;
      f32x4 acc[4];
#pragma unroll
      for (int nt = 0; nt < 4; ++nt) acc[nt] = (f32x4){0.f, 0.f, 0.f, 0.f};
#pragma unroll
      for (int ks = 0; ks < 8; ++ks) {
        const float4 xa = *(const float4*)(xr + ks * 32);
        const float4 xb = *(const float4*)(xr + ks * 32 + 4);
        union { short8 v; u32 u[4]; } A;
        A.u[0] = packbf(xa.x, xa.y);
        A.u[1] = packbf(xa.z, xa.w);
        A.u[2] = packbf(xb.x, xb.y);
        A.u[3] = packbf(xb.z, xb.w);
#pragma unroll
        for (int nt = 0; nt < 4; ++nt) {
          const short8 Bv = *(const short8*)(Bf + (size_t)((ks * 4 + nt) * 64 + lane) * 4);
          acc[nt] = __builtin_amdgcn_mfma_f32_16x16x32_bf16(A.v, Bv, acc[nt], 0, 0, 0);
        }
      }
      // C/D layout: col = nt*16 + m(l15), row = tt*16 + q*4 + reg (session-verified)
#pragma unroll
      for (int nt = 0; nt < 4; ++nt)
#pragma unroll
        for (int reg = 0; reg < 4; ++reg)
          preL[(tt * 16 + q * 4 + reg) * PSTRIDE + nt * 16 + l15] = f2bf(acc[nt][reg] + cw[nt]);
    }
  }
  __syncthreads();

  // ================= scan phase: wave w owns chunks B*64 + w*16 + l15 (2 rows each) ==========
  {
    typedef union { short8 v; u32 u[4]; uint4 u4; } Frag;

    // A1[t4]: A[n1=16*t4+l15][k=e] = W1[256+e][n1]  (k<8 -> only quad 0 nonzero)
    Frag A1[4];
#pragma unroll
    for (int t4 = 0; t4 < 4; ++t4)
#pragma unroll
      for (int i = 0; i < 4; ++i) {
        u32 pk = 0;
        if (q == 0) {
          const int n1 = 16 * t4 + l15;
          pk = packbf(W1[(size_t)(256 + 2 * i) * 64 + n1],
                      W1[(size_t)(256 + 2 * i + 1) * 64 + n1]);
        }
        A1[t4].u[i] = pk;
      }
    // A2[m2][hf]: A[n2=16*m2+l15][k1=32*hf+8q+e] = W2[k1][n2]
    Frag A2[2][2];
#pragma unroll
    for (int m2 = 0; m2 < 2; ++m2)
#pragma unroll
      for (int hf = 0; hf < 2; ++hf)
#pragma unroll
        for (int i = 0; i < 4; ++i) {
          const int n2 = 16 * m2 + l15;
          const int k0 = 32 * hf + 8 * q + 2 * i;
          A2[m2][hf].u[i] = packbf(W2[k0 * 32 + n2], W2[(k0 + 1) * 32 + n2]);
        }
    // A3: A[o=l15][k2=8q+e] = W3[k2][o]  (rows o>=8 zeroed; their D rows are discarded)
    Frag A3;
    {
      const int o = l15 & 7;
#pragma unroll
      for (int i = 0; i < 4; ++i) {
        const int k0 = 8 * q + 2 * i;
        const u32 pk = packbf(W3[k0 * 8 + o], W3[(k0 + 1) * 8 + o]);
        A3.u[i] = (l15 < 8) ? pk : 0;
      }
    }
    // biases as MFMA C operands (row r = 4q+reg)
    f32x4 b2c[2], b3c;
#pragma unroll
    for (int m2 = 0; m2 < 2; ++m2) {
      const float4 t = *(const float4*)(b2 + 16 * m2 + 4 * q);
      b2c[m2] = (f32x4){t.x, t.y, t.z, t.w};
    }
    {
      const float4 t = *(const float4*)(b3 + 4 * (q & 1));   // q>=2 rows discarded
      b3c = (f32x4){t.x, t.y, t.z, t.w};
    }

    u16*       l1w = &sL1[w][l15 * 88 + 4 * q];
    const u16* l1r = &sL1[w][l15 * 88 + 8 * q];
    u16*       l2w = &sL2[w][l15 * 40 + 4 * q];
    const u16* l2r = &sL2[w][l15 * 40 + 8 * q];
    u16*       l3w = &sL3[w][l15 * 8 + 4 * q];
    const u16* l3r = &sL3[w][l15 * 8];

    if (lane < 16) *(uint4*)&sL3[w][lane * 8] = make_uint4(0, 0, 0, 0);
    __builtin_amdgcn_wave_barrier();

    const int cg_ = B * 64 + w * 16 + l15;   // this lane's global chunk
    // preL row for (chunk, t): (w*16+l15)*2 + t + 8  (>= 0 for t >= -8)
    const u16* preRow = &preL[(size_t)((w * 16 + l15) * SC_CHUNK + 8) * PSTRIDE + 4 * q];
    auto ldpre = [&](int t) {
      P4 r;
      const u16* pr = preRow + t * PSTRIDE;
#pragma unroll
      for (int t4 = 0; t4 < 4; ++t4) r.v[t4] = *(const uint2*)(pr + 16 * t4);
      return r;
    };

    uint4 sv = make_uint4(0, 0, 0, 0);       // quads 0,1 save rows 0,1 of the chunk
    P4 pc = ldpre(-WARM);
#pragma unroll 2
    for (int t = -WARM; t < SC_CHUNK; ++t) {
      const int tn = (t + 1 < SC_CHUNK - 1) ? t + 1 : SC_CHUNK - 1;
      const P4 pn = ldpre(tn);               // prefetch next step's pre

      // feedback read: h(t-1) for all 16 chunks
      Frag hv; hv.u4 = *(const uint4*)l3r;
      const bool mt = (t - 1 >= 0) && (q == t - 1);
      sv = mt ? hv.u4 : sv;

      // exact-start reset: global row (cg_*2 + t) == 0 -> h := 0 for that chunk.
      // Fires mid-warm (t=-2*cg_) for cg_<4, making the row-0-crossing chunks exact.
      const bool rz = (cg_ * SC_CHUNK + t == 0);
      Frag b1f;
#pragma unroll
      for (int i = 0; i < 4; ++i) b1f.u[i] = (q == 0 && !rz) ? hv.u[i] : 0;
      __builtin_amdgcn_wave_barrier();

      // layer 1: D1[n1][m] = Wh^T h + pre  (C carries pre), relu, pack to L1[m][k1]
#pragma unroll
      for (int t4 = 0; t4 < 4; ++t4) {
        const uint2 pp = pc.v[t4];
        const f32x4 C = (f32x4){bfl(pp.x), bfh(pp.x), bfl(pp.y), bfh(pp.y)};
        const f32x4 d = __builtin_amdgcn_mfma_f32_16x16x32_bf16(A1[t4].v, b1f.v, C, 0, 0, 0);
        uint2 wv;
        wv.x = packbf(fmaxf(d[0], 0.f), fmaxf(d[1], 0.f));
        wv.y = packbf(fmaxf(d[2], 0.f), fmaxf(d[3], 0.f));
        *(uint2*)(l1w + 16 * t4) = wv;
      }
      __builtin_amdgcn_wave_barrier();
      short8 h1f0 = *(const short8*)(l1r);
      short8 h1f1 = *(const short8*)(l1r + 32);
      __builtin_amdgcn_wave_barrier();

      // layer 2: D2[n2][m] = W2^T h1 + b2, relu, pack to L2[m][k2]
#pragma unroll
      for (int m2 = 0; m2 < 2; ++m2) {
        f32x4 d = __builtin_amdgcn_mfma_f32_16x16x32_bf16(A2[m2][0].v, h1f0, b2c[m2], 0, 0, 0);
        d = __builtin_amdgcn_mfma_f32_16x16x32_bf16(A2[m2][1].v, h1f1, d, 0, 0, 0);
        uint2 wv;
        wv.x = packbf(fmaxf(d[0], 0.f), fmaxf(d[1], 0.f));
        wv.y = packbf(fmaxf(d[2], 0.f), fmaxf(d[3], 0.f));
        *(uint2*)(l2w + 16 * m2) = wv;
      }
      __builtin_amdgcn_wave_barrier();
      short8 h2f = *(const short8*)l2r;
      __builtin_amdgcn_wave_barrier();

      // layer 3: D3[o][m] = W3^T h2 + b3 -> h(t), pack to L3[m][o]
      const f32x4 d3 = __builtin_amdgcn_mfma_f32_16x16x32_bf16(A3.v, h2f, b3c, 0, 0, 0);
      if (q < 2) {
        uint2 wv;
        wv.x = packbf(d3[0], d3[1]);
        wv.y = packbf(d3[2], d3[3]);
        *(uint2*)l3w = wv;
      }
      __builtin_amdgcn_wave_barrier();
      pc = pn;
    }
    {                                        // h(1) final save (q==1)
      Frag hv; hv.u4 = *(const uint4*)l3r;
      if (q == 1) sv = hv.u4;
    }

    // epilogue: lane(q<2,l15) owns chunk cg_ row q -> out[cg_*2 + q][0..8)
    if (q < 2) {
      const size_t row = (size_t)cg_ * SC_CHUNK + q;
      float4* dst = (float4*)(out + row * 8);
      dst[0] = make_float4(bfl(sv.x), bfh(sv.x), bfl(sv.y), bfh(sv.y));
      dst[1] = make_float4(bfl(sv.z), bfh(sv.z), bfl(sv.w), bfh(sv.w));
    }
  }
}

extern "C" void kernel_launch(void* const* d_in, const int* in_sizes, int n_in,
                              void* d_out, int out_size, void* d_ws, size_t ws_size,
                              hipStream_t stream) {
  (void)in_sizes; (void)n_in; (void)out_size;
  const float* x     = (const float*)d_in[0];
  const float* gamma = (const float*)d_in[1];
  const float* beta  = (const float*)d_in[2];
  const float* W1    = (const float*)d_in[3];
  const float* b1    = (const float*)d_in[4];
  const float* W2    = (const float*)d_in[5];
  const float* b2    = (const float*)d_in[6];
  const float* W3    = (const float*)d_in[7];
  const float* b3    = (const float*)d_in[8];
  float* out = (float*)d_out;
  float* ws  = (float*)d_ws;

  if (ws_size < WS_NEED) {               // diagnosable failure: absmax ~12345
    k_sentinel<<<1, 64, 0, stream>>>(out);
    return;
  }
  k_zero     <<<1,         512, 0, stream>>>(ws);
  k_stats    <<<1024,      256, 0, stream>>>(x, ws);
  k_prep     <<<1,         512, 0, stream>>>(gamma, beta, W1, b1, ws);
  k_gemm_scan<<<NBLK_SCAN, 256, 0, stream>>>(x, ws, W1, W2, b2, W3, b3, out);
}

// Round 6
// 288.952 us; speedup vs baseline: 1.0271x; 1.0271x over previous
//
#include <hip/hip_runtime.h>
#include <hip/hip_bf16.h>

typedef unsigned short u16;
typedef unsigned int   u32;
typedef __attribute__((ext_vector_type(8))) short short8;   // 8 bf16 (4 VGPRs)
typedef __attribute__((ext_vector_type(4))) float f32x4;

#define T_ROWS    131072
#define SC_CHUNK  2            // rows per chunk in the fused scan
#define WARM      8            // rho<=0.34 -> 0.34^8 ~ 1.8e-4
#define NBLK_SCAN 1024         // 1024 blocks * 4 waves * 16 chunks * 2 rows = 131072
#define PSTRIDE   70           // preL row stride in u16
#define PTILES    9            // 9 tiles of 16 rows = 144 >= 128 + 8 warm
#define PROWS     (PTILES * 16)

// ws layout (float offsets)
#define WS_SUM   0             // 256 f
#define WS_SQ    256           // 256 f
#define WS_CJ    512           // 64 f  (b1 + shift@W1 folded)
#define WS_WEF   576           // 8192 u32: We bf16 in MFMA B-frag order [ks*4+nt][lane][j(8)]
#define WS_NEED  ((size_t)(WS_WEF + 8192) * 4)                // ~35 KB

__device__ __forceinline__ u16 f2bf(float f) {   // RNE float->bf16
  u32 u = __float_as_uint(f);
  u += 0x7FFFu + ((u >> 16) & 1u);
  return (u16)(u >> 16);
}
__device__ __forceinline__ u32 packbf(float a, float b) {
  return (u32)f2bf(a) | ((u32)f2bf(b) << 16);
}
__device__ __forceinline__ float bfl(u32 u) { return __uint_as_float(u << 16); }
__device__ __forceinline__ float bfh(u32 u) { return __uint_as_float(u & 0xFFFF0000u); }

__global__ void k_zero(float* ws) { ws[threadIdx.x] = 0.0f; }   // <<<1,512>>>

__global__ void k_sentinel(float* out) { out[threadIdx.x] = 12345.0f; }

// ---- column mean / sumsq over x[131072][256], grid 1024 x 256 thr (proven) ----
__global__ __launch_bounds__(256) void k_stats(const float* __restrict__ x,
                                               float* __restrict__ ws) {
  __shared__ float lsum[1024];
  __shared__ float lsq[1024];
  const int tid = threadIdx.x;
  const int lane = tid & 63;
  const int w = tid >> 6;
  const int c = lane * 4;
  float s0 = 0, s1 = 0, s2 = 0, s3 = 0;
  float q0 = 0, q1 = 0, q2 = 0, q3 = 0;
  const size_t rbase = (size_t)blockIdx.x * 128;
#pragma unroll 4
  for (int i = w; i < 128; i += 4) {
    const float4 v = *(const float4*)(x + (rbase + i) * 256 + c);
    s0 += v.x; s1 += v.y; s2 += v.z; s3 += v.w;
    q0 = fmaf(v.x, v.x, q0); q1 = fmaf(v.y, v.y, q1);
    q2 = fmaf(v.z, v.z, q2); q3 = fmaf(v.w, v.w, q3);
  }
  lsum[w * 256 + c + 0] = s0; lsum[w * 256 + c + 1] = s1;
  lsum[w * 256 + c + 2] = s2; lsum[w * 256 + c + 3] = s3;
  lsq [w * 256 + c + 0] = q0; lsq [w * 256 + c + 1] = q1;
  lsq [w * 256 + c + 2] = q2; lsq [w * 256 + c + 3] = q3;
  __syncthreads();
  const float ts = lsum[tid] + lsum[256 + tid] + lsum[512 + tid] + lsum[768 + tid];
  const float tq = lsq [tid] + lsq [256 + tid] + lsq [512 + tid] + lsq [768 + tid];
  atomicAdd(ws + WS_SUM + tid, ts);
  atomicAdd(ws + WS_SQ  + tid, tq);
}

// ---- fold BN into weights. Emits We = scale*W1[:256] in MFMA B-frag order. 512 thr. (proven) ----
__global__ __launch_bounds__(512) void k_prep(const float* __restrict__ gamma,
                                              const float* __restrict__ beta,
                                              const float* __restrict__ W1,
                                              const float* __restrict__ b1,
                                              float* __restrict__ ws) {
  __shared__ float sScale[256];
  __shared__ float sShift[256];
  __shared__ float sCj[512];
  const int tid = threadIdx.x;
  if (tid < 256) {
    const float inv = 1.0f / (float)T_ROWS;
    const float mean = ws[WS_SUM + tid] * inv;
    const float var  = ws[WS_SQ + tid] * inv - mean * mean;   // biased, keras BN
    const float sc = gamma[tid] * rsqrtf(var + 1e-3f);
    sScale[tid] = sc;
    sShift[tid] = beta[tid] - mean * sc;
  }
  __syncthreads();
  if (tid < 256) {
    const int nt = tid >> 6;
    const int lane = tid & 63;
    const int m = lane & 15;
    const int q = lane >> 4;
    const int n = nt * 16 + m;
    u32* Wf = (u32*)(ws + WS_WEF);
#pragma unroll
    for (int ks = 0; ks < 8; ++ks) {
      uint4 pk;
      u32 w_[4];
#pragma unroll
      for (int jj = 0; jj < 4; ++jj) {
        const int k0 = ks * 32 + q * 8 + 2 * jj;
        const u32 lo = f2bf(sScale[k0]     * W1[(size_t)k0 * 64 + n]);
        const u32 hi = f2bf(sScale[k0 + 1] * W1[(size_t)(k0 + 1) * 64 + n]);
        w_[jj] = lo | (hi << 16);
      }
      pk.x = w_[0]; pk.y = w_[1]; pk.z = w_[2]; pk.w = w_[3];
      *(uint4*)(Wf + (size_t)((ks * 4 + nt) * 64 + lane) * 4) = pk;
    }
  }
  // cj[j] = b1[j] + sum_c sShift[c]*W1[c][j], 8-way split over c then LDS combine
  const int j = tid & 63;
  const int part = tid >> 6;            // 0..7
  float p = (part == 0) ? b1[j] : 0.0f;
  for (int c = part * 32; c < part * 32 + 32; ++c)
    p = fmaf(sShift[c], W1[(size_t)c * 64 + j], p);
  sCj[tid] = p;
  __syncthreads();
  if (tid < 64) {
    float a = 0.0f;
#pragma unroll
    for (int k = 0; k < 8; ++k) a += sCj[k * 64 + tid];
    ws[WS_CJ + tid] = a;
  }
}

// ---- FUSED gemm+scan: 1024 blocks x (128 rows + 8 warm). LDS 37.6 KB -> 4 blocks/CU.
//      launch_bounds(256,2): round-5's (256,4) clamped to 64 VGPR and spilled ~220B/thread
//      (WRITE_SIZE 63.8 MB vs 4 MB expected). 88-VGPR allocation still fits 4 waves/SIMD
//      (occupancy step at 128), so the lower bound costs nothing and kills the spill. ----
struct P4 { uint2 v[4]; };

__global__ __launch_bounds__(256, 2) void k_gemm_scan(
    const float* __restrict__ x, const float* __restrict__ ws,
    const float* __restrict__ W1, const float* __restrict__ W2,
    const float* __restrict__ b2, const float* __restrict__ W3,
    const float* __restrict__ b3, float* __restrict__ out) {
  __shared__ __align__(16) u16 preL[PROWS * PSTRIDE];   // 20160 B
  __shared__ __align__(16) u16 sL1[4][16 * 88];         // 11264 B, per-wave h1 tile
  __shared__ __align__(16) u16 sL2[4][16 * 40];         //  5120 B, per-wave h2 tile
  __shared__ __align__(16) u16 sL3[4][16 * 8];          //  1024 B, per-wave h tile

  const int lane = threadIdx.x & 63;
  const int w    = threadIdx.x >> 6;
  const int l15  = lane & 15;
  const int q    = lane >> 4;
  const int B    = blockIdx.x;

  // ================= GEMM phase: 9 tiles of 16 rows into preL =================
  {
    const u32* Bf = (const u32*)(ws + WS_WEF);
    float cw[4];
#pragma unroll
    for (int nt = 0; nt < 4; ++nt) cw[nt] = ws[WS_CJ + nt * 16 + l15];
    const int rowOrigin = B * 128 - 8;
    for (int tt = w; tt < PTILES; tt += 4) {
      int gr = rowOrigin + tt * 16 + l15;               // clamp: edge rows junk, unused/reset
      gr = gr < 0 ? 0 : (gr > T_ROWS - 1 ? T_ROWS - 1 : gr);
      const float* xr = x + (size_t)gr * 256 + q * 8;
      f32x4 acc[4];
#pragma unroll
      for (int nt = 0; nt < 4; ++nt) acc[nt] = (f32x4){0.f, 0.f, 0.f, 0.f};
#pragma unroll
      for (int ks = 0; ks < 8; ++ks) {
        const float4 xa = *(const float4*)(xr + ks * 32);
        const float4 xb = *(const float4*)(xr + ks * 32 + 4);
        union { short8 v; u32 u[4]; } A;
        A.u[0] = packbf(xa.x, xa.y);
        A.u[1] = packbf(xa.z, xa.w);
        A.u[2] = packbf(xb.x, xb.y);
        A.u[3] = packbf(xb.z, xb.w);
#pragma unroll
        for (int nt = 0; nt < 4; ++nt) {
          const short8 Bv = *(const short8*)(Bf + (size_t)((ks * 4 + nt) * 64 + lane) * 4);
          acc[nt] = __builtin_amdgcn_mfma_f32_16x16x32_bf16(A.v, Bv, acc[nt], 0, 0, 0);
        }
      }
      // C/D layout: col = nt*16 + m(l15), row = tt*16 + q*4 + reg (session-verified)
#pragma unroll
      for (int nt = 0; nt < 4; ++nt)
#pragma unroll
        for (int reg = 0; reg < 4; ++reg)
          preL[(tt * 16 + q * 4 + reg) * PSTRIDE + nt * 16 + l15] = f2bf(acc[nt][reg] + cw[nt]);
    }
  }
  __syncthreads();

  // ================= scan phase: wave w owns chunks B*64 + w*16 + l15 (2 rows each) ==========
  {
    typedef union { short8 v; u32 u[4]; uint4 u4; } Frag;

    // A1[t4]: A[n1=16*t4+l15][k=e] = W1[256+e][n1]  (k<8 -> only quad 0 nonzero)
    Frag A1[4];
#pragma unroll
    for (int t4 = 0; t4 < 4; ++t4)
#pragma unroll
      for (int i = 0; i < 4; ++i) {
        u32 pk = 0;
        if (q == 0) {
          const int n1 = 16 * t4 + l15;
          pk = packbf(W1[(size_t)(256 + 2 * i) * 64 + n1],
                      W1[(size_t)(256 + 2 * i + 1) * 64 + n1]);
        }
        A1[t4].u[i] = pk;
      }
    // A2[m2][hf]: A[n2=16*m2+l15][k1=32*hf+8q+e] = W2[k1][n2]
    Frag A2[2][2];
#pragma unroll
    for (int m2 = 0; m2 < 2; ++m2)
#pragma unroll
      for (int hf = 0; hf < 2; ++hf)
#pragma unroll
        for (int i = 0; i < 4; ++i) {
          const int n2 = 16 * m2 + l15;
          const int k0 = 32 * hf + 8 * q + 2 * i;
          A2[m2][hf].u[i] = packbf(W2[k0 * 32 + n2], W2[(k0 + 1) * 32 + n2]);
        }
    // A3: A[o=l15][k2=8q+e] = W3[k2][o]  (rows o>=8 zeroed; their D rows are discarded)
    Frag A3;
    {
      const int o = l15 & 7;
#pragma unroll
      for (int i = 0; i < 4; ++i) {
        const int k0 = 8 * q + 2 * i;
        const u32 pk = packbf(W3[k0 * 8 + o], W3[(k0 + 1) * 8 + o]);
        A3.u[i] = (l15 < 8) ? pk : 0;
      }
    }
    // biases as MFMA C operands (row r = 4q+reg)
    f32x4 b2c[2], b3c;
#pragma unroll
    for (int m2 = 0; m2 < 2; ++m2) {
      const float4 t = *(const float4*)(b2 + 16 * m2 + 4 * q);
      b2c[m2] = (f32x4){t.x, t.y, t.z, t.w};
    }
    {
      const float4 t = *(const float4*)(b3 + 4 * (q & 1));   // q>=2 rows discarded
      b3c = (f32x4){t.x, t.y, t.z, t.w};
    }

    u16*       l1w = &sL1[w][l15 * 88 + 4 * q];
    const u16* l1r = &sL1[w][l15 * 88 + 8 * q];
    u16*       l2w = &sL2[w][l15 * 40 + 4 * q];
    const u16* l2r = &sL2[w][l15 * 40 + 8 * q];
    u16*       l3w = &sL3[w][l15 * 8 + 4 * q];
    const u16* l3r = &sL3[w][l15 * 8];

    if (lane < 16) *(uint4*)&sL3[w][lane * 8] = make_uint4(0, 0, 0, 0);
    __builtin_amdgcn_wave_barrier();

    const int cg_ = B * 64 + w * 16 + l15;   // this lane's global chunk
    // preL row for (chunk, t): (w*16+l15)*2 + t + 8  (>= 0 for t >= -8)
    const u16* preRow = &preL[(size_t)((w * 16 + l15) * SC_CHUNK + 8) * PSTRIDE + 4 * q];
    auto ldpre = [&](int t) {
      P4 r;
      const u16* pr = preRow + t * PSTRIDE;
#pragma unroll
      for (int t4 = 0; t4 < 4; ++t4) r.v[t4] = *(const uint2*)(pr + 16 * t4);
      return r;
    };

    uint4 sv = make_uint4(0, 0, 0, 0);       // quads 0,1 save rows 0,1 of the chunk
    P4 pc = ldpre(-WARM);
#pragma unroll 2
    for (int t = -WARM; t < SC_CHUNK; ++t) {
      const int tn = (t + 1 < SC_CHUNK - 1) ? t + 1 : SC_CHUNK - 1;
      const P4 pn = ldpre(tn);               // prefetch next step's pre

      // feedback read: h(t-1) for all 16 chunks
      Frag hv; hv.u4 = *(const uint4*)l3r;
      const bool mt = (t - 1 >= 0) && (q == t - 1);
      sv = mt ? hv.u4 : sv;

      // exact-start reset: global row (cg_*2 + t) == 0 -> h := 0 for that chunk.
      // Fires mid-warm (t=-2*cg_) for cg_<4, making the row-0-crossing chunks exact.
      const bool rz = (cg_ * SC_CHUNK + t == 0);
      Frag b1f;
#pragma unroll
      for (int i = 0; i < 4; ++i) b1f.u[i] = (q == 0 && !rz) ? hv.u[i] : 0;
      __builtin_amdgcn_wave_barrier();

      // layer 1: D1[n1][m] = Wh^T h + pre  (C carries pre), relu, pack to L1[m][k1]
#pragma unroll
      for (int t4 = 0; t4 < 4; ++t4) {
        const uint2 pp = pc.v[t4];
        const f32x4 C = (f32x4){bfl(pp.x), bfh(pp.x), bfl(pp.y), bfh(pp.y)};
        const f32x4 d = __builtin_amdgcn_mfma_f32_16x16x32_bf16(A1[t4].v, b1f.v, C, 0, 0, 0);
        uint2 wv;
        wv.x = packbf(fmaxf(d[0], 0.f), fmaxf(d[1], 0.f));
        wv.y = packbf(fmaxf(d[2], 0.f), fmaxf(d[3], 0.f));
        *(uint2*)(l1w + 16 * t4) = wv;
      }
      __builtin_amdgcn_wave_barrier();
      short8 h1f0 = *(const short8*)(l1r);
      short8 h1f1 = *(const short8*)(l1r + 32);
      __builtin_amdgcn_wave_barrier();

      // layer 2: D2[n2][m] = W2^T h1 + b2, relu, pack to L2[m][k2]
#pragma unroll
      for (int m2 = 0; m2 < 2; ++m2) {
        f32x4 d = __builtin_amdgcn_mfma_f32_16x16x32_bf16(A2[m2][0].v, h1f0, b2c[m2], 0, 0, 0);
        d = __builtin_amdgcn_mfma_f32_16x16x32_bf16(A2[m2][1].v, h1f1, d, 0, 0, 0);
        uint2 wv;
        wv.x = packbf(fmaxf(d[0], 0.f), fmaxf(d[1], 0.f));
        wv.y = packbf(fmaxf(d[2], 0.f), fmaxf(d[3], 0.f));
        *(uint2*)(l2w + 16 * m2) = wv;
      }
      __builtin_amdgcn_wave_barrier();
      short8 h2f = *(const short8*)l2r;
      __builtin_amdgcn_wave_barrier();

      // layer 3: D3[o][m] = W3^T h2 + b3 -> h(t), pack to L3[m][o]
      const f32x4 d3 = __builtin_amdgcn_mfma_f32_16x16x32_bf16(A3.v, h2f, b3c, 0, 0, 0);
      if (q < 2) {
        uint2 wv;
        wv.x = packbf(d3[0], d3[1]);
        wv.y = packbf(d3[2], d3[3]);
        *(uint2*)l3w = wv;
      }
      __builtin_amdgcn_wave_barrier();
      pc = pn;
    }
    {                                        // h(1) final save (q==1)
      Frag hv; hv.u4 = *(const uint4*)l3r;
      if (q == 1) sv = hv.u4;
    }

    // epilogue: lane(q<2,l15) owns chunk cg_ row q -> out[cg_*2 + q][0..8)
    if (q < 2) {
      const size_t row = (size_t)cg_ * SC_CHUNK + q;
      float4* dst = (float4*)(out + row * 8);
      dst[0] = make_float4(bfl(sv.x), bfh(sv.x), bfl(sv.y), bfh(sv.y));
      dst[1] = make_float4(bfl(sv.z), bfh(sv.z), bfl(sv.w), bfh(sv.w));
    }
  }
}

extern "C" void kernel_launch(void* const* d_in, const int* in_sizes, int n_in,
                              void* d_out, int out_size, void* d_ws, size_t ws_size,
                              hipStream_t stream) {
  (void)in_sizes; (void)n_in; (void)out_size;
  const float* x     = (const float*)d_in[0];
  const float* gamma = (const float*)d_in[1];
  const float* beta  = (const float*)d_in[2];
  const float* W1    = (const float*)d_in[3];
  const float* b1    = (const float*)d_in[4];
  const float* W2    = (const float*)d_in[5];
  const float* b2    = (const float*)d_in[6];
  const float* W3    = (const float*)d_in[7];
  const float* b3    = (const float*)d_in[8];
  float* out = (float*)d_out;
  float* ws  = (float*)d_ws;

  if (ws_size < WS_NEED) {               // diagnosable failure: absmax ~12345
    k_sentinel<<<1, 64, 0, stream>>>(out);
    return;
  }
  k_zero     <<<1,         512, 0, stream>>>(ws);
  k_stats    <<<1024,      256, 0, stream>>>(x, ws);
  k_prep     <<<1,         512, 0, stream>>>(gamma, beta, W1, b1, ws);
  k_gemm_scan<<<NBLK_SCAN, 256, 0, stream>>>(x, ws, W1, W2, b2, W3, b3, out);
}

// Round 7
// 269.263 us; speedup vs baseline: 1.1022x; 1.0731x over previous
//
#include <hip/hip_runtime.h>
#include <hip/hip_bf16.h>

typedef unsigned short u16;
typedef unsigned int   u32;
typedef __attribute__((ext_vector_type(8))) short short8;   // 8 bf16 (4 VGPRs)
typedef __attribute__((ext_vector_type(4))) float f32x4;

#define T_ROWS    131072
#define SC_CHUNK  4            // rows per chunk in the fused scan (4 beats 2: warm amortization, R6)
#define WARM      8            // rho<=0.34 -> 0.34^8 ~ 1.8e-4
#define NBLK_SCAN 512          // 512 blocks * 4 waves * 16 chunks * 4 rows = 131072
#define PSTRIDE   70           // preL row stride in u16 (2-way banks on scan pre-reads)
#define PTILES    17           // 17 tiles of 16 rows = 272 >= 256 + 8 warm

// ws layout (float offsets)
#define WS_SUM   0             // 256 f
#define WS_SQ    256           // 256 f
#define WS_CJ    512           // 64 f  (b1 + shift@W1 folded)
#define WS_WEF   576           // 8192 u32: We bf16 in MFMA B-frag order [ks*4+nt][lane][j(8)]
#define WS_NEED  ((size_t)(WS_WEF + 8192) * 4)                // ~35 KB

__device__ __forceinline__ u16 f2bf(float f) {   // RNE float->bf16
  u32 u = __float_as_uint(f);
  u += 0x7FFFu + ((u >> 16) & 1u);
  return (u16)(u >> 16);
}
__device__ __forceinline__ u32 packbf(float a, float b) {
  return (u32)f2bf(a) | ((u32)f2bf(b) << 16);
}
__device__ __forceinline__ float bfl(u32 u) { return __uint_as_float(u << 16); }
__device__ __forceinline__ float bfh(u32 u) { return __uint_as_float(u & 0xFFFF0000u); }

__global__ void k_sentinel(float* out) { out[threadIdx.x] = 12345.0f; }

// ---- column mean / sumsq over x[131072][256], grid 1024 x 256 thr (proven) ----
__global__ __launch_bounds__(256) void k_stats(const float* __restrict__ x,
                                               float* __restrict__ ws) {
  __shared__ float lsum[1024];
  __shared__ float lsq[1024];
  const int tid = threadIdx.x;
  const int lane = tid & 63;
  const int w = tid >> 6;
  const int c = lane * 4;
  float s0 = 0, s1 = 0, s2 = 0, s3 = 0;
  float q0 = 0, q1 = 0, q2 = 0, q3 = 0;
  const size_t rbase = (size_t)blockIdx.x * 128;
#pragma unroll 4
  for (int i = w; i < 128; i += 4) {
    const float4 v = *(const float4*)(x + (rbase + i) * 256 + c);
    s0 += v.x; s1 += v.y; s2 += v.z; s3 += v.w;
    q0 = fmaf(v.x, v.x, q0); q1 = fmaf(v.y, v.y, q1);
    q2 = fmaf(v.z, v.z, q2); q3 = fmaf(v.w, v.w, q3);
  }
  lsum[w * 256 + c + 0] = s0; lsum[w * 256 + c + 1] = s1;
  lsum[w * 256 + c + 2] = s2; lsum[w * 256 + c + 3] = s3;
  lsq [w * 256 + c + 0] = q0; lsq [w * 256 + c + 1] = q1;
  lsq [w * 256 + c + 2] = q2; lsq [w * 256 + c + 3] = q3;
  __syncthreads();
  const float ts = lsum[tid] + lsum[256 + tid] + lsum[512 + tid] + lsum[768 + tid];
  const float tq = lsq [tid] + lsq [256 + tid] + lsq [512 + tid] + lsq [768 + tid];
  atomicAdd(ws + WS_SUM + tid, ts);
  atomicAdd(ws + WS_SQ  + tid, tq);
}

// ---- fold BN into weights. Emits We = scale*W1[:256] in MFMA B-frag order. 512 thr. (proven) ----
__global__ __launch_bounds__(512) void k_prep(const float* __restrict__ gamma,
                                              const float* __restrict__ beta,
                                              const float* __restrict__ W1,
                                              const float* __restrict__ b1,
                                              float* __restrict__ ws) {
  __shared__ float sScale[256];
  __shared__ float sShift[256];
  __shared__ float sCj[512];
  const int tid = threadIdx.x;
  if (tid < 256) {
    const float inv = 1.0f / (float)T_ROWS;
    const float mean = ws[WS_SUM + tid] * inv;
    const float var  = ws[WS_SQ + tid] * inv - mean * mean;   // biased, keras BN
    const float sc = gamma[tid] * rsqrtf(var + 1e-3f);
    sScale[tid] = sc;
    sShift[tid] = beta[tid] - mean * sc;
  }
  __syncthreads();
  if (tid < 256) {
    const int nt = tid >> 6;
    const int lane = tid & 63;
    const int m = lane & 15;
    const int q = lane >> 4;
    const int n = nt * 16 + m;
    u32* Wf = (u32*)(ws + WS_WEF);
#pragma unroll
    for (int ks = 0; ks < 8; ++ks) {
      uint4 pk;
      u32 w_[4];
#pragma unroll
      for (int jj = 0; jj < 4; ++jj) {
        const int k0 = ks * 32 + q * 8 + 2 * jj;
        const u32 lo = f2bf(sScale[k0]     * W1[(size_t)k0 * 64 + n]);
        const u32 hi = f2bf(sScale[k0 + 1] * W1[(size_t)(k0 + 1) * 64 + n]);
        w_[jj] = lo | (hi << 16);
      }
      pk.x = w_[0]; pk.y = w_[1]; pk.z = w_[2]; pk.w = w_[3];
      *(uint4*)(Wf + (size_t)((ks * 4 + nt) * 64 + lane) * 4) = pk;
    }
  }
  // cj[j] = b1[j] + sum_c sShift[c]*W1[c][j], 8-way split over c then LDS combine
  const int j = tid & 63;
  const int part = tid >> 6;            // 0..7
  float p = (part == 0) ? b1[j] : 0.0f;
  for (int c = part * 32; c < part * 32 + 32; ++c)
    p = fmaf(sShift[c], W1[(size_t)c * 64 + j], p);
  sCj[tid] = p;
  __syncthreads();
  if (tid < 64) {
    float a = 0.0f;
#pragma unroll
    for (int k = 0; k < 8; ++k) a += sCj[k * 64 + tid];
    ws[WS_CJ + tid] = a;
  }
}

// ---- FUSED gemm+scan, R3 geometry (512 blocks x 256 rows + 8 warm, SC_CHUNK=4).
//      GEMM phase: x tiles register-double-buffered (tile t+4 loads issued before tile t's
//      compute) -> 2x in-flight bytes; R5 PMC showed x re-read at 2.3 TB/s (36% of peak),
//      classic MLP starvation. Bh hoist dropped to keep VGPR < 256 (no spill). ----
struct P4 { uint2 v[4]; };
struct XT { float4 a[8]; float4 b[8]; };   // one 16-row x tile slice per lane, 64 VGPRs

__global__ __launch_bounds__(256, 2) void k_gemm_scan(
    const float* __restrict__ x, const float* __restrict__ ws,
    const float* __restrict__ W1, const float* __restrict__ W2,
    const float* __restrict__ b2, const float* __restrict__ W3,
    const float* __restrict__ b3, float* __restrict__ out) {
  __shared__ __align__(16) u16 preL[272 * PSTRIDE];     // 38080 B
  __shared__ __align__(16) u16 sL1[4][16 * 88];         // 11264 B, per-wave h1 tile
  __shared__ __align__(16) u16 sL2[4][16 * 40];         //  5120 B, per-wave h2 tile
  __shared__ __align__(16) u16 sL3[4][16 * 8];          //  1024 B, per-wave h tile

  const int lane = threadIdx.x & 63;
  const int w    = threadIdx.x >> 6;
  const int l15  = lane & 15;
  const int q    = lane >> 4;
  const int B    = blockIdx.x;

  // ================= GEMM phase: 17 tiles of 16 rows into preL =================
  {
    const u32* Bf = (const u32*)(ws + WS_WEF);
    float cw[4];
#pragma unroll
    for (int nt = 0; nt < 4; ++nt) cw[nt] = ws[WS_CJ + nt * 16 + l15];
    const int rowOrigin = B * 256 - 8;

    auto ldtile = [&](int tt) {
      XT r;
      int gr = rowOrigin + tt * 16 + l15;               // clamp: edge rows junk, unused/reset
      gr = gr < 0 ? 0 : (gr > T_ROWS - 1 ? T_ROWS - 1 : gr);
      const float* xr = x + (size_t)gr * 256 + q * 8;
#pragma unroll
      for (int ks = 0; ks < 8; ++ks) {
        r.a[ks] = *(const float4*)(xr + ks * 32);
        r.b[ks] = *(const float4*)(xr + ks * 32 + 4);
      }
      return r;
    };

    XT cur = ldtile(w);
    for (int tt = w; tt < PTILES; tt += 4) {
      const int tnx = (tt + 4 < PTILES) ? tt + 4 : tt;  // last iter: redundant reload, valid
      XT nxt = ldtile(tnx);                             // 16 loads in flight over the compute
      f32x4 acc[4];
#pragma unroll
      for (int nt = 0; nt < 4; ++nt) acc[nt] = (f32x4){0.f, 0.f, 0.f, 0.f};
#pragma unroll
      for (int ks = 0; ks < 8; ++ks) {
        const float4 xa = cur.a[ks];
        const float4 xb = cur.b[ks];
        union { short8 v; u32 u[4]; } A;
        A.u[0] = packbf(xa.x, xa.y);
        A.u[1] = packbf(xa.z, xa.w);
        A.u[2] = packbf(xb.x, xb.y);
        A.u[3] = packbf(xb.z, xb.w);
#pragma unroll
        for (int nt = 0; nt < 4; ++nt) {
          const short8 Bv = *(const short8*)(Bf + (size_t)((ks * 4 + nt) * 64 + lane) * 4);
          acc[nt] = __builtin_amdgcn_mfma_f32_16x16x32_bf16(A.v, Bv, acc[nt], 0, 0, 0);
        }
      }
      // C/D layout: col = nt*16 + m(l15), row = tt*16 + q*4 + reg (session-verified)
#pragma unroll
      for (int nt = 0; nt < 4; ++nt)
#pragma unroll
        for (int reg = 0; reg < 4; ++reg)
          preL[(tt * 16 + q * 4 + reg) * PSTRIDE + nt * 16 + l15] = f2bf(acc[nt][reg] + cw[nt]);
      cur = nxt;
    }
  }
  __syncthreads();

  // ================= scan phase: wave w owns chunks B*64 + w*16 + l15 (4 rows each) ==========
  {
    typedef union { short8 v; u32 u[4]; uint4 u4; } Frag;

    // A1[t4]: A[n1=16*t4+l15][k=e] = W1[256+e][n1]  (k<8 -> only quad 0 nonzero)
    Frag A1[4];
#pragma unroll
    for (int t4 = 0; t4 < 4; ++t4)
#pragma unroll
      for (int i = 0; i < 4; ++i) {
        u32 pk = 0;
        if (q == 0) {
          const int n1 = 16 * t4 + l15;
          pk = packbf(W1[(size_t)(256 + 2 * i) * 64 + n1],
                      W1[(size_t)(256 + 2 * i + 1) * 64 + n1]);
        }
        A1[t4].u[i] = pk;
      }
    // A2[m2][hf]: A[n2=16*m2+l15][k1=32*hf+8q+e] = W2[k1][n2]
    Frag A2[2][2];
#pragma unroll
    for (int m2 = 0; m2 < 2; ++m2)
#pragma unroll
      for (int hf = 0; hf < 2; ++hf)
#pragma unroll
        for (int i = 0; i < 4; ++i) {
          const int n2 = 16 * m2 + l15;
          const int k0 = 32 * hf + 8 * q + 2 * i;
          A2[m2][hf].u[i] = packbf(W2[k0 * 32 + n2], W2[(k0 + 1) * 32 + n2]);
        }
    // A3: A[o=l15][k2=8q+e] = W3[k2][o]  (rows o>=8 zeroed; their D rows are discarded)
    Frag A3;
    {
      const int o = l15 & 7;
#pragma unroll
      for (int i = 0; i < 4; ++i) {
        const int k0 = 8 * q + 2 * i;
        const u32 pk = packbf(W3[k0 * 8 + o], W3[(k0 + 1) * 8 + o]);
        A3.u[i] = (l15 < 8) ? pk : 0;
      }
    }
    // biases as MFMA C operands (row r = 4q+reg)
    f32x4 b2c[2], b3c;
#pragma unroll
    for (int m2 = 0; m2 < 2; ++m2) {
      const float4 t = *(const float4*)(b2 + 16 * m2 + 4 * q);
      b2c[m2] = (f32x4){t.x, t.y, t.z, t.w};
    }
    {
      const float4 t = *(const float4*)(b3 + 4 * (q & 1));   // q>=2 rows discarded
      b3c = (f32x4){t.x, t.y, t.z, t.w};
    }

    u16*       l1w = &sL1[w][l15 * 88 + 4 * q];
    const u16* l1r = &sL1[w][l15 * 88 + 8 * q];
    u16*       l2w = &sL2[w][l15 * 40 + 4 * q];
    const u16* l2r = &sL2[w][l15 * 40 + 8 * q];
    u16*       l3w = &sL3[w][l15 * 8 + 4 * q];
    const u16* l3r = &sL3[w][l15 * 8];

    if (lane < 16) *(uint4*)&sL3[w][lane * 8] = make_uint4(0, 0, 0, 0);
    __builtin_amdgcn_wave_barrier();

    const int cg_ = B * 64 + w * 16 + l15;   // this lane's global chunk
    // preL row for (chunk, t): (w*16+l15)*4 + t + 8  (>= 0 for t >= -8)
    const u16* preRow = &preL[(size_t)((w * 16 + l15) * SC_CHUNK + 8) * PSTRIDE + 4 * q];
    auto ldpre = [&](int t) {
      P4 r;
      const u16* pr = preRow + t * PSTRIDE;
#pragma unroll
      for (int t4 = 0; t4 < 4; ++t4) r.v[t4] = *(const uint2*)(pr + 16 * t4);
      return r;
    };

    uint4 sv = make_uint4(0, 0, 0, 0);       // each quad saves exactly one output row
    P4 pc = ldpre(-WARM);
#pragma unroll 2
    for (int t = -WARM; t < SC_CHUNK; ++t) {
      const int tn = (t + 1 < SC_CHUNK - 1) ? t + 1 : SC_CHUNK - 1;
      const P4 pn = ldpre(tn);               // prefetch next step's pre

      // feedback read: h(t-1) for all 16 chunks
      Frag hv; hv.u4 = *(const uint4*)l3r;
      const bool mt = (t - 1 >= 0) && (q == t - 1);
      sv = mt ? hv.u4 : sv;

      // exact-start reset: global row (cg_*4 + t) == 0 -> h := 0 for that chunk
      const bool rz = (cg_ * SC_CHUNK + t == 0);
      Frag b1f;
#pragma unroll
      for (int i = 0; i < 4; ++i) b1f.u[i] = (q == 0 && !rz) ? hv.u[i] : 0;
      __builtin_amdgcn_wave_barrier();

      // layer 1: D1[n1][m] = Wh^T h + pre  (C carries pre), relu, pack to L1[m][k1]
#pragma unroll
      for (int t4 = 0; t4 < 4; ++t4) {
        const uint2 pp = pc.v[t4];
        const f32x4 C = (f32x4){bfl(pp.x), bfh(pp.x), bfl(pp.y), bfh(pp.y)};
        const f32x4 d = __builtin_amdgcn_mfma_f32_16x16x32_bf16(A1[t4].v, b1f.v, C, 0, 0, 0);
        uint2 wv;
        wv.x = packbf(fmaxf(d[0], 0.f), fmaxf(d[1], 0.f));
        wv.y = packbf(fmaxf(d[2], 0.f), fmaxf(d[3], 0.f));
        *(uint2*)(l1w + 16 * t4) = wv;
      }
      __builtin_amdgcn_wave_barrier();
      short8 h1f0 = *(const short8*)(l1r);
      short8 h1f1 = *(const short8*)(l1r + 32);
      __builtin_amdgcn_wave_barrier();

      // layer 2: D2[n2][m] = W2^T h1 + b2, relu, pack to L2[m][k2]
#pragma unroll
      for (int m2 = 0; m2 < 2; ++m2) {
        f32x4 d = __builtin_amdgcn_mfma_f32_16x16x32_bf16(A2[m2][0].v, h1f0, b2c[m2], 0, 0, 0);
        d = __builtin_amdgcn_mfma_f32_16x16x32_bf16(A2[m2][1].v, h1f1, d, 0, 0, 0);
        uint2 wv;
        wv.x = packbf(fmaxf(d[0], 0.f), fmaxf(d[1], 0.f));
        wv.y = packbf(fmaxf(d[2], 0.f), fmaxf(d[3], 0.f));
        *(uint2*)(l2w + 16 * m2) = wv;
      }
      __builtin_amdgcn_wave_barrier();
      short8 h2f = *(const short8*)l2r;
      __builtin_amdgcn_wave_barrier();

      // layer 3: D3[o][m] = W3^T h2 + b3 -> h(t), pack to L3[m][o]
      const f32x4 d3 = __builtin_amdgcn_mfma_f32_16x16x32_bf16(A3.v, h2f, b3c, 0, 0, 0);
      if (q < 2) {
        uint2 wv;
        wv.x = packbf(d3[0], d3[1]);
        wv.y = packbf(d3[2], d3[3]);
        *(uint2*)l3w = wv;
      }
      __builtin_amdgcn_wave_barrier();
      pc = pn;
    }
    {                                        // h(3) final save (q==3)
      Frag hv; hv.u4 = *(const uint4*)l3r;
      if (q == 3) sv = hv.u4;
    }

    // epilogue: lane(q,l15) owns chunk cg_ row q -> out[cg_*4 + q][0..8)
    const size_t row = (size_t)cg_ * SC_CHUNK + q;
    float4* dst = (float4*)(out + row * 8);
    dst[0] = make_float4(bfl(sv.x), bfh(sv.x), bfl(sv.y), bfh(sv.y));
    dst[1] = make_float4(bfl(sv.z), bfh(sv.z), bfl(sv.w), bfh(sv.w));
  }
}

extern "C" void kernel_launch(void* const* d_in, const int* in_sizes, int n_in,
                              void* d_out, int out_size, void* d_ws, size_t ws_size,
                              hipStream_t stream) {
  (void)in_sizes; (void)n_in; (void)out_size;
  const float* x     = (const float*)d_in[0];
  const float* gamma = (const float*)d_in[1];
  const float* beta  = (const float*)d_in[2];
  const float* W1    = (const float*)d_in[3];
  const float* b1    = (const float*)d_in[4];
  const float* W2    = (const float*)d_in[5];
  const float* b2    = (const float*)d_in[6];
  const float* W3    = (const float*)d_in[7];
  const float* b3    = (const float*)d_in[8];
  float* out = (float*)d_out;
  float* ws  = (float*)d_ws;

  if (ws_size < WS_NEED) {               // diagnosable failure: absmax ~12345
    k_sentinel<<<1, 64, 0, stream>>>(out);
    return;
  }
  hipMemsetAsync(ws, 0, 512 * sizeof(float), stream);   // WS_SUM + WS_SQ (replaces k_zero)
  k_stats    <<<1024,      256, 0, stream>>>(x, ws);
  k_prep     <<<1,         512, 0, stream>>>(gamma, beta, W1, b1, ws);
  k_gemm_scan<<<NBLK_SCAN, 256, 0, stream>>>(x, ws, W1, W2, b2, W3, b3, out);
}

// Round 8
// 257.272 us; speedup vs baseline: 1.1535x; 1.0466x over previous
//
#include <hip/hip_runtime.h>
#include <hip/hip_bf16.h>

typedef unsigned short u16;
typedef unsigned int   u32;
typedef __attribute__((ext_vector_type(8))) short short8;   // 8 bf16 (4 VGPRs)
typedef __attribute__((ext_vector_type(4))) float f32x4;

#define T_ROWS    131072
#define SC_CHUNK  4            // rows per chunk in the fused scan (4 beats 2: warm amortization, R6)
#define WARM      8            // rho<=0.34 -> 0.34^8 ~ 1.8e-4
#define NBLK_SCAN 512          // 512 blocks * 4 waves * 16 chunks * 4 rows = 131072
#define PSTRIDE   70           // preL row stride in u16 (2-way banks on scan pre-reads)
#define PTILES    17           // 17 tiles of 16 rows = 272 >= 256 + 8 warm

// ws layout (float offsets), then xb (bf16 copy of x) at byte offset WS_XB_BYTES
#define WS_SUM   0             // 256 f
#define WS_SQ    256           // 256 f
#define WS_CJ    512           // 64 f  (b1 + shift@W1 folded)
#define WS_WEF   576           // 8192 u32: We bf16 in MFMA B-frag order [ks*4+nt][lane][j(8)]
#define WS_XB_BYTES ((size_t)(WS_WEF + 8192) * 4)             // 35072 B, 16-aligned
#define XB_BYTES    ((size_t)T_ROWS * 256 * 2)                // 67.1 MB bf16 x
#define WS_NEED  (WS_XB_BYTES + XB_BYTES)

__device__ __forceinline__ u16 f2bf(float f) {   // RNE float->bf16
  u32 u = __float_as_uint(f);
  u += 0x7FFFu + ((u >> 16) & 1u);
  return (u16)(u >> 16);
}
__device__ __forceinline__ u32 packbf(float a, float b) {
  return (u32)f2bf(a) | ((u32)f2bf(b) << 16);
}
__device__ __forceinline__ float bfl(u32 u) { return __uint_as_float(u << 16); }
__device__ __forceinline__ float bfh(u32 u) { return __uint_as_float(u & 0xFFFF0000u); }

__global__ void k_sentinel(float* out) { out[threadIdx.x] = 12345.0f; }

// ---- column mean/sumsq over x[131072][256] + emit bf16(x) to xb (coalesced).
//      x is consumed by the GEMM only as bf16 (identical RNE cast), so converting here
//      halves the GEMM phase's HBM fetch: 134 -> 67 MB.  grid 1024 x 256 thr. ----
__global__ __launch_bounds__(256) void k_stats(const float* __restrict__ x,
                                               float* __restrict__ ws,
                                               uint2* __restrict__ xb) {
  __shared__ float lsum[1024];
  __shared__ float lsq[1024];
  const int tid = threadIdx.x;
  const int lane = tid & 63;
  const int w = tid >> 6;
  const int c = lane * 4;
  float s0 = 0, s1 = 0, s2 = 0, s3 = 0;
  float q0 = 0, q1 = 0, q2 = 0, q3 = 0;
  const size_t rbase = (size_t)blockIdx.x * 128;
#pragma unroll 4
  for (int i = w; i < 128; i += 4) {
    const float4 v = *(const float4*)(x + (rbase + i) * 256 + c);
    s0 += v.x; s1 += v.y; s2 += v.z; s3 += v.w;
    q0 = fmaf(v.x, v.x, q0); q1 = fmaf(v.y, v.y, q1);
    q2 = fmaf(v.z, v.z, q2); q3 = fmaf(v.w, v.w, q3);
    xb[(rbase + i) * 64 + lane] = make_uint2(packbf(v.x, v.y), packbf(v.z, v.w));
  }
  lsum[w * 256 + c + 0] = s0; lsum[w * 256 + c + 1] = s1;
  lsum[w * 256 + c + 2] = s2; lsum[w * 256 + c + 3] = s3;
  lsq [w * 256 + c + 0] = q0; lsq [w * 256 + c + 1] = q1;
  lsq [w * 256 + c + 2] = q2; lsq [w * 256 + c + 3] = q3;
  __syncthreads();
  const float ts = lsum[tid] + lsum[256 + tid] + lsum[512 + tid] + lsum[768 + tid];
  const float tq = lsq [tid] + lsq [256 + tid] + lsq [512 + tid] + lsq [768 + tid];
  atomicAdd(ws + WS_SUM + tid, ts);
  atomicAdd(ws + WS_SQ  + tid, tq);
}

// ---- fold BN into weights. Emits We = scale*W1[:256] in MFMA B-frag order. 512 thr. (proven) ----
__global__ __launch_bounds__(512) void k_prep(const float* __restrict__ gamma,
                                              const float* __restrict__ beta,
                                              const float* __restrict__ W1,
                                              const float* __restrict__ b1,
                                              float* __restrict__ ws) {
  __shared__ float sScale[256];
  __shared__ float sShift[256];
  __shared__ float sCj[512];
  const int tid = threadIdx.x;
  if (tid < 256) {
    const float inv = 1.0f / (float)T_ROWS;
    const float mean = ws[WS_SUM + tid] * inv;
    const float var  = ws[WS_SQ + tid] * inv - mean * mean;   // biased, keras BN
    const float sc = gamma[tid] * rsqrtf(var + 1e-3f);
    sScale[tid] = sc;
    sShift[tid] = beta[tid] - mean * sc;
  }
  __syncthreads();
  if (tid < 256) {
    const int nt = tid >> 6;
    const int lane = tid & 63;
    const int m = lane & 15;
    const int q = lane >> 4;
    const int n = nt * 16 + m;
    u32* Wf = (u32*)(ws + WS_WEF);
#pragma unroll
    for (int ks = 0; ks < 8; ++ks) {
      uint4 pk;
      u32 w_[4];
#pragma unroll
      for (int jj = 0; jj < 4; ++jj) {
        const int k0 = ks * 32 + q * 8 + 2 * jj;
        const u32 lo = f2bf(sScale[k0]     * W1[(size_t)k0 * 64 + n]);
        const u32 hi = f2bf(sScale[k0 + 1] * W1[(size_t)(k0 + 1) * 64 + n]);
        w_[jj] = lo | (hi << 16);
      }
      pk.x = w_[0]; pk.y = w_[1]; pk.z = w_[2]; pk.w = w_[3];
      *(uint4*)(Wf + (size_t)((ks * 4 + nt) * 64 + lane) * 4) = pk;
    }
  }
  // cj[j] = b1[j] + sum_c sShift[c]*W1[c][j], 8-way split over c then LDS combine
  const int j = tid & 63;
  const int part = tid >> 6;            // 0..7
  float p = (part == 0) ? b1[j] : 0.0f;
  for (int c = part * 32; c < part * 32 + 32; ++c)
    p = fmaf(sShift[c], W1[(size_t)c * 64 + j], p);
  sCj[tid] = p;
  __syncthreads();
  if (tid < 64) {
    float a = 0.0f;
#pragma unroll
    for (int k = 0; k < 8; ++k) a += sCj[k * 64 + tid];
    ws[WS_CJ + tid] = a;
  }
}

// ---- FUSED gemm+scan, R3 geometry. GEMM reads bf16 xb (half bytes), Bh hoisted
//      to registers (no per-tile L2 B-reads), no packbf in the inner loop. ----
struct P4 { uint2 v[4]; };
struct XTB { uint4 v[8]; };   // one 16-row bf16 tile slice per lane, 32 VGPRs

__global__ __launch_bounds__(256, 2) void k_gemm_scan(
    const u32* __restrict__ xb, const float* __restrict__ ws,
    const float* __restrict__ W1, const float* __restrict__ W2,
    const float* __restrict__ b2, const float* __restrict__ W3,
    const float* __restrict__ b3, float* __restrict__ out) {
  __shared__ __align__(16) u16 preL[272 * PSTRIDE];     // 38080 B
  __shared__ __align__(16) u16 sL1[4][16 * 88];         // 11264 B, per-wave h1 tile
  __shared__ __align__(16) u16 sL2[4][16 * 40];         //  5120 B, per-wave h2 tile
  __shared__ __align__(16) u16 sL3[4][16 * 8];          //  1024 B, per-wave h tile

  const int lane = threadIdx.x & 63;
  const int w    = threadIdx.x >> 6;
  const int l15  = lane & 15;
  const int q    = lane >> 4;
  const int B    = blockIdx.x;

  // ================= GEMM phase: 17 tiles of 16 rows into preL =================
  {
    const u32* Bf = (const u32*)(ws + WS_WEF);
    short8 Bh[8][4];                         // all 32 B-frags in VGPRs (128), read once
#pragma unroll
    for (int ks = 0; ks < 8; ++ks)
#pragma unroll
      for (int nt = 0; nt < 4; ++nt)
        Bh[ks][nt] = *(const short8*)(Bf + (size_t)((ks * 4 + nt) * 64 + lane) * 4);

    float cw[4];
#pragma unroll
    for (int nt = 0; nt < 4; ++nt) cw[nt] = ws[WS_CJ + nt * 16 + l15];
    const int rowOrigin = B * 256 - 8;

    auto ldtile = [&](int tt) {
      XTB r;
      int gr = rowOrigin + tt * 16 + l15;               // clamp: edge rows junk, unused/reset
      gr = gr < 0 ? 0 : (gr > T_ROWS - 1 ? T_ROWS - 1 : gr);
      const u32* xr = xb + (size_t)gr * 128 + q * 4;    // bf16 row = 128 u32
#pragma unroll
      for (int ks = 0; ks < 8; ++ks) r.v[ks] = *(const uint4*)(xr + ks * 16);
      return r;
    };

    XTB cur = ldtile(w);
    for (int tt = w; tt < PTILES; tt += 4) {
      const int tnx = (tt + 4 < PTILES) ? tt + 4 : tt;  // last iter: redundant reload, valid
      XTB nxt = ldtile(tnx);
      f32x4 acc[4];
#pragma unroll
      for (int nt = 0; nt < 4; ++nt) acc[nt] = (f32x4){0.f, 0.f, 0.f, 0.f};
#pragma unroll
      for (int ks = 0; ks < 8; ++ks) {
        union { short8 v; uint4 u4; } A;
        A.u4 = cur.v[ks];
#pragma unroll
        for (int nt = 0; nt < 4; ++nt)
          acc[nt] = __builtin_amdgcn_mfma_f32_16x16x32_bf16(A.v, Bh[ks][nt], acc[nt], 0, 0, 0);
      }
      // C/D layout: col = nt*16 + m(l15), row = tt*16 + q*4 + reg (session-verified)
#pragma unroll
      for (int nt = 0; nt < 4; ++nt)
#pragma unroll
        for (int reg = 0; reg < 4; ++reg)
          preL[(tt * 16 + q * 4 + reg) * PSTRIDE + nt * 16 + l15] = f2bf(acc[nt][reg] + cw[nt]);
      cur = nxt;
    }
  }
  __syncthreads();

  // ================= scan phase: wave w owns chunks B*64 + w*16 + l15 (4 rows each) ==========
  {
    typedef union { short8 v; u32 u[4]; uint4 u4; } Frag;

    // A1[t4]: A[n1=16*t4+l15][k=e] = W1[256+e][n1]  (k<8 -> only quad 0 nonzero)
    Frag A1[4];
#pragma unroll
    for (int t4 = 0; t4 < 4; ++t4)
#pragma unroll
      for (int i = 0; i < 4; ++i) {
        u32 pk = 0;
        if (q == 0) {
          const int n1 = 16 * t4 + l15;
          pk = packbf(W1[(size_t)(256 + 2 * i) * 64 + n1],
                      W1[(size_t)(256 + 2 * i + 1) * 64 + n1]);
        }
        A1[t4].u[i] = pk;
      }
    // A2[m2][hf]: A[n2=16*m2+l15][k1=32*hf+8q+e] = W2[k1][n2]
    Frag A2[2][2];
#pragma unroll
    for (int m2 = 0; m2 < 2; ++m2)
#pragma unroll
      for (int hf = 0; hf < 2; ++hf)
#pragma unroll
        for (int i = 0; i < 4; ++i) {
          const int n2 = 16 * m2 + l15;
          const int k0 = 32 * hf + 8 * q + 2 * i;
          A2[m2][hf].u[i] = packbf(W2[k0 * 32 + n2], W2[(k0 + 1) * 32 + n2]);
        }
    // A3: A[o=l15][k2=8q+e] = W3[k2][o]  (rows o>=8 zeroed; their D rows are discarded)
    Frag A3;
    {
      const int o = l15 & 7;
#pragma unroll
      for (int i = 0; i < 4; ++i) {
        const int k0 = 8 * q + 2 * i;
        const u32 pk = packbf(W3[k0 * 8 + o], W3[(k0 + 1) * 8 + o]);
        A3.u[i] = (l15 < 8) ? pk : 0;
      }
    }
    // biases as MFMA C operands (row r = 4q+reg)
    f32x4 b2c[2], b3c;
#pragma unroll
    for (int m2 = 0; m2 < 2; ++m2) {
      const float4 t = *(const float4*)(b2 + 16 * m2 + 4 * q);
      b2c[m2] = (f32x4){t.x, t.y, t.z, t.w};
    }
    {
      const float4 t = *(const float4*)(b3 + 4 * (q & 1));   // q>=2 rows discarded
      b3c = (f32x4){t.x, t.y, t.z, t.w};
    }

    u16*       l1w = &sL1[w][l15 * 88 + 4 * q];
    const u16* l1r = &sL1[w][l15 * 88 + 8 * q];
    u16*       l2w = &sL2[w][l15 * 40 + 4 * q];
    const u16* l2r = &sL2[w][l15 * 40 + 8 * q];
    u16*       l3w = &sL3[w][l15 * 8 + 4 * q];
    const u16* l3r = &sL3[w][l15 * 8];

    if (lane < 16) *(uint4*)&sL3[w][lane * 8] = make_uint4(0, 0, 0, 0);
    __builtin_amdgcn_wave_barrier();

    const int cg_ = B * 64 + w * 16 + l15;   // this lane's global chunk
    // preL row for (chunk, t): (w*16+l15)*4 + t + 8  (>= 0 for t >= -8)
    const u16* preRow = &preL[(size_t)((w * 16 + l15) * SC_CHUNK + 8) * PSTRIDE + 4 * q];
    auto ldpre = [&](int t) {
      P4 r;
      const u16* pr = preRow + t * PSTRIDE;
#pragma unroll
      for (int t4 = 0; t4 < 4; ++t4) r.v[t4] = *(const uint2*)(pr + 16 * t4);
      return r;
    };

    uint4 sv = make_uint4(0, 0, 0, 0);       // each quad saves exactly one output row
    P4 pc = ldpre(-WARM);
#pragma unroll 2
    for (int t = -WARM; t < SC_CHUNK; ++t) {
      const int tn = (t + 1 < SC_CHUNK - 1) ? t + 1 : SC_CHUNK - 1;
      const P4 pn = ldpre(tn);               // prefetch next step's pre

      // feedback read: h(t-1) for all 16 chunks
      Frag hv; hv.u4 = *(const uint4*)l3r;
      const bool mt = (t - 1 >= 0) && (q == t - 1);
      sv = mt ? hv.u4 : sv;

      // exact-start reset: global row (cg_*4 + t) == 0 -> h := 0 for that chunk
      const bool rz = (cg_ * SC_CHUNK + t == 0);
      Frag b1f;
#pragma unroll
      for (int i = 0; i < 4; ++i) b1f.u[i] = (q == 0 && !rz) ? hv.u[i] : 0;
      __builtin_amdgcn_wave_barrier();

      // layer 1: D1[n1][m] = Wh^T h + pre  (C carries pre), relu, pack to L1[m][k1]
#pragma unroll
      for (int t4 = 0; t4 < 4; ++t4) {
        const uint2 pp = pc.v[t4];
        const f32x4 C = (f32x4){bfl(pp.x), bfh(pp.x), bfl(pp.y), bfh(pp.y)};
        const f32x4 d = __builtin_amdgcn_mfma_f32_16x16x32_bf16(A1[t4].v, b1f.v, C, 0, 0, 0);
        uint2 wv;
        wv.x = packbf(fmaxf(d[0], 0.f), fmaxf(d[1], 0.f));
        wv.y = packbf(fmaxf(d[2], 0.f), fmaxf(d[3], 0.f));
        *(uint2*)(l1w + 16 * t4) = wv;
      }
      __builtin_amdgcn_wave_barrier();
      short8 h1f0 = *(const short8*)(l1r);
      short8 h1f1 = *(const short8*)(l1r + 32);
      __builtin_amdgcn_wave_barrier();

      // layer 2: D2[n2][m] = W2^T h1 + b2, relu, pack to L2[m][k2]
#pragma unroll
      for (int m2 = 0; m2 < 2; ++m2) {
        f32x4 d = __builtin_amdgcn_mfma_f32_16x16x32_bf16(A2[m2][0].v, h1f0, b2c[m2], 0, 0, 0);
        d = __builtin_amdgcn_mfma_f32_16x16x32_bf16(A2[m2][1].v, h1f1, d, 0, 0, 0);
        uint2 wv;
        wv.x = packbf(fmaxf(d[0], 0.f), fmaxf(d[1], 0.f));
        wv.y = packbf(fmaxf(d[2], 0.f), fmaxf(d[3], 0.f));
        *(uint2*)(l2w + 16 * m2) = wv;
      }
      __builtin_amdgcn_wave_barrier();
      short8 h2f = *(const short8*)l2r;
      __builtin_amdgcn_wave_barrier();

      // layer 3: D3[o][m] = W3^T h2 + b3 -> h(t), pack to L3[m][o]
      const f32x4 d3 = __builtin_amdgcn_mfma_f32_16x16x32_bf16(A3.v, h2f, b3c, 0, 0, 0);
      if (q < 2) {
        uint2 wv;
        wv.x = packbf(d3[0], d3[1]);
        wv.y = packbf(d3[2], d3[3]);
        *(uint2*)l3w = wv;
      }
      __builtin_amdgcn_wave_barrier();
      pc = pn;
    }
    {                                        // h(3) final save (q==3)
      Frag hv; hv.u4 = *(const uint4*)l3r;
      if (q == 3) sv = hv.u4;
    }

    // epilogue: lane(q,l15) owns chunk cg_ row q -> out[cg_*4 + q][0..8)
    const size_t row = (size_t)cg_ * SC_CHUNK + q;
    float4* dst = (float4*)(out + row * 8);
    dst[0] = make_float4(bfl(sv.x), bfh(sv.x), bfl(sv.y), bfh(sv.y));
    dst[1] = make_float4(bfl(sv.z), bfh(sv.z), bfl(sv.w), bfh(sv.w));
  }
}

extern "C" void kernel_launch(void* const* d_in, const int* in_sizes, int n_in,
                              void* d_out, int out_size, void* d_ws, size_t ws_size,
                              hipStream_t stream) {
  (void)in_sizes; (void)n_in; (void)out_size;
  const float* x     = (const float*)d_in[0];
  const float* gamma = (const float*)d_in[1];
  const float* beta  = (const float*)d_in[2];
  const float* W1    = (const float*)d_in[3];
  const float* b1    = (const float*)d_in[4];
  const float* W2    = (const float*)d_in[5];
  const float* b2    = (const float*)d_in[6];
  const float* W3    = (const float*)d_in[7];
  const float* b3    = (const float*)d_in[8];
  float* out = (float*)d_out;
  float* ws  = (float*)d_ws;
  u32*  xb   = (u32*)((char*)d_ws + WS_XB_BYTES);

  if (ws_size < WS_NEED) {               // diagnosable failure: absmax ~12345
    k_sentinel<<<1, 64, 0, stream>>>(out);
    return;
  }
  hipMemsetAsync(ws, 0, 512 * sizeof(float), stream);   // WS_SUM + WS_SQ
  k_stats    <<<1024,      256, 0, stream>>>(x, ws, (uint2*)xb);
  k_prep     <<<1,         512, 0, stream>>>(gamma, beta, W1, b1, ws);
  k_gemm_scan<<<NBLK_SCAN, 256, 0, stream>>>(xb, ws, W1, W2, b2, W3, b3, out);
}